// Round 14
// baseline (68.201 us; speedup 1.0000x reference)
//
#include <hip/hip_runtime.h>
#include <hip/hip_fp16.h>

#define CDIM 512
#define ROWS 65536

typedef _Float16 half8  __attribute__((ext_vector_type(8)));
typedef __fp16   fp16x2 __attribute__((ext_vector_type(2)));
typedef float    f32x16 __attribute__((ext_vector_type(16)));

// async global->LDS, 16B per lane; LDS dest = wave-uniform base + lane*16
#define GLD_LDS16(gp, lp) __builtin_amdgcn_global_load_lds( \
    (const __attribute__((address_space(1))) unsigned int*)(gp), \
    (__attribute__((address_space(3))) unsigned int*)(lp), 16, 0, 0)

__device__ __forceinline__ half8 cvt8(float4 f0, float4 f1) {
    union { fp16x2 h2[4]; half8 h8; } u;
    u.h2[0] = __builtin_amdgcn_cvt_pkrtz(f0.x, f0.y);
    u.h2[1] = __builtin_amdgcn_cvt_pkrtz(f0.z, f0.w);
    u.h2[2] = __builtin_amdgcn_cvt_pkrtz(f1.x, f1.y);
    u.h2[3] = __builtin_amdgcn_cvt_pkrtz(f1.z, f1.w);
    return u.h8;
}

// ---------------- K1 (fused): blocks 0..31 qproj, blocks 32..159 wkfrag ----------------
__global__ void prep_kernel(const float* __restrict__ Q, const float* __restrict__ Wq,
                            const float* __restrict__ bq, const float* __restrict__ Wout,
                            const float* __restrict__ Wk,
                            float* __restrict__ v, _Float16* __restrict__ Wkf) {
    __shared__ float qs[CDIM];
    const int t = threadIdx.x;
    if (blockIdx.x < 32) {
        // v[j] = relu(Q.Wq[j,:]+bq[j]) * Wout[j/64] / 8 ; bout dropped (softmax shift-invariant)
        qs[t] = Q[t]; qs[t + 256] = Q[t + 256];
        __syncthreads();
        const int jj  = t >> 4;
        const int sub = t & 15;
        const int j   = blockIdx.x * 16 + jj;
        const float4* w4 = (const float4*)(Wq + (size_t)j * CDIM + sub * 32);
        const float4* q4 = (const float4*)(qs + sub * 32);
        float s = 0.f;
        #pragma unroll
        for (int i = 0; i < 8; ++i) {
            float4 w = w4[i]; float4 q = q4[i];
            s = fmaf(w.x, q.x, s); s = fmaf(w.y, q.y, s);
            s = fmaf(w.z, q.z, s); s = fmaf(w.w, q.w, s);
        }
        s += __shfl_xor(s, 1); s += __shfl_xor(s, 2);
        s += __shfl_xor(s, 4); s += __shfl_xor(s, 8);
        if (sub == 0) {
            s += bq[j];
            s = fmaxf(s, 0.f);
            v[j] = s * Wout[j >> 6] * 0.125f;
        }
    } else {
        // Wk -> fp16 B-fragments [jb 0..15][kc 0..31][lane 0..63][8 halfs]
        // frag(jb,kc) lane l: B[k=kc*16+(l>>5)*8+e][j=jb*32+(l&31)]
        const int gid = (blockIdx.x - 32) * 256 + t;
        const int jb  = gid >> 11;
        const int kc  = (gid >> 6) & 31;
        const int l   = gid & 63;
        const int j   = jb * 32 + (l & 31);
        const int k   = kc * 16 + (l >> 5) * 8;
        const float* src = Wk + (size_t)j * CDIM + k;
        float4 f0 = *(const float4*)(src);
        float4 f1 = *(const float4*)(src + 4);
        *(half8*)(Wkf + (size_t)gid * 8) = cvt8(f0, f1);
    }
}

// ---------------- K2: dual-A-in-regs (64 rows/wave), B 64j-chunks via DMA LDS ------------
// 256 WGs x 256 thr (4 waves, 1 wave/SIMD). Wave w owns rows bid*256 + w*64 .. +63
// as two A-blocks a0/a1 (full K, 256 VGPRs). Each B-frag read feeds 2 MFMAs ->
// per-CU LDS traffic halved to 2MB. A loaded INSIDE chunk 0 (8 interleaved batches)
// so the K-read burst hides under compute. 8 chunks x 64 j, dbuf 2x64KB DMA, 8 barriers.
__global__ __launch_bounds__(256, 1) void score_kernel(
    const float* __restrict__ Kmat, const _Float16* __restrict__ Wkf,
    const float* __restrict__ bk, const float* __restrict__ v,
    float* __restrict__ logits)
{
    __shared__ alignas(16) char Bb[2][65536];   // 2 x (2 jb x 32 kc x 64 lanes x 16B)

    const int tid  = threadIdx.x;
    const int lane = tid & 63;
    const int wave = tid >> 6;          // 0..3
    const int l31  = lane & 31;
    const int lhi  = lane >> 5;
    const int rowbase = blockIdx.x * 256;

    // ---- issue chunk-0 DMA first ----
    #pragma unroll
    for (int i = 0; i < 16; ++i)
        GLD_LDS16((const char*)Wkf + i * 4096 + tid * 16, Bb[0] + i * 4096 + tid * 16);

    const float* ab0 = Kmat + (size_t)(rowbase + wave * 64 + l31) * CDIM + lhi * 8;
    const float* ab1 = ab0 + 32 * CDIM;

    half8 a0[32], a1[32];
    float part0[16], part1[16];
    #pragma unroll
    for (int r = 0; r < 16; ++r) { part0[r] = 0.f; part1[r] = 0.f; }

    __syncthreads();   // chunk 0 landed

    for (int c = 0; c < 8; ++c) {
        const int cur = c & 1;

        // DMA chunk c+1 (in flight across this chunk's compute)
        if (c < 7) {
            const char* src = (const char*)Wkf + (size_t)(c + 1) * 65536;
            #pragma unroll
            for (int i = 0; i < 16; ++i)
                GLD_LDS16(src + i * 4096 + tid * 16, Bb[cur ^ 1] + i * 4096 + tid * 16);
        }

        const int jg = c * 64 + l31;
        const float bj0 = bk[jg],      vj0 = v[jg];
        const float bj1 = bk[jg + 32], vj1 = v[jg + 32];

        f32x16 acc00, acc01, acc10, acc11;
        #pragma unroll
        for (int r = 0; r < 16; ++r) { acc00[r]=0.f; acc01[r]=0.f; acc10[r]=0.f; acc11[r]=0.f; }

        if (c == 0) {
            // chunk 0: interleave A-loading (8 batches of 4 kc) with compute
            #pragma unroll
            for (int q = 0; q < 8; ++q) {
                #pragma unroll
                for (int i = 0; i < 4; ++i) {
                    const int kc = q * 4 + i;
                    float4 f00 = *(const float4*)(ab0 + kc * 16);
                    float4 f01 = *(const float4*)(ab0 + kc * 16 + 4);
                    float4 f10 = *(const float4*)(ab1 + kc * 16);
                    float4 f11 = *(const float4*)(ab1 + kc * 16 + 4);
                    a0[kc] = cvt8(f00, f01);
                    a1[kc] = cvt8(f10, f11);
                }
                #pragma unroll
                for (int i = 0; i < 4; ++i) {
                    const int kc = q * 4 + i;
                    half8 b0 = *(const half8*)(Bb[0] + kc * 1024 + lane * 16);
                    half8 b1 = *(const half8*)(Bb[0] + (32 + kc) * 1024 + lane * 16);
                    acc00 = __builtin_amdgcn_mfma_f32_32x32x16_f16(a0[kc], b0, acc00, 0, 0, 0);
                    acc01 = __builtin_amdgcn_mfma_f32_32x32x16_f16(a0[kc], b1, acc01, 0, 0, 0);
                    acc10 = __builtin_amdgcn_mfma_f32_32x32x16_f16(a1[kc], b0, acc10, 0, 0, 0);
                    acc11 = __builtin_amdgcn_mfma_f32_32x32x16_f16(a1[kc], b1, acc11, 0, 0, 0);
                }
            }
        } else {
            // steady chunks: 64 conflict-free reads feed 128 MFMAs
            #pragma unroll
            for (int kc = 0; kc < 32; ++kc) {
                half8 b0 = *(const half8*)(Bb[cur] + kc * 1024 + lane * 16);
                half8 b1 = *(const half8*)(Bb[cur] + (32 + kc) * 1024 + lane * 16);
                acc00 = __builtin_amdgcn_mfma_f32_32x32x16_f16(a0[kc], b0, acc00, 0, 0, 0);
                acc01 = __builtin_amdgcn_mfma_f32_32x32x16_f16(a0[kc], b1, acc01, 0, 0, 0);
                acc10 = __builtin_amdgcn_mfma_f32_32x32x16_f16(a1[kc], b0, acc10, 0, 0, 0);
                acc11 = __builtin_amdgcn_mfma_f32_32x32x16_f16(a1[kc], b1, acc11, 0, 0, 0);
            }
        }

        #pragma unroll
        for (int r = 0; r < 16; ++r) {
            part0[r] += fmaxf(acc00[r] + bj0, 0.f) * vj0 + fmaxf(acc01[r] + bj1, 0.f) * vj1;
            part1[r] += fmaxf(acc10[r] + bj0, 0.f) * vj0 + fmaxf(acc11[r] + bj1, 0.f) * vj1;
        }

        __syncthreads();   // drains DMA + reads before buffer swap
    }

    // ---- epilogue: fold-tree per A-block; write this wave's 64 rows ----
    #pragma unroll
    for (int g = 0; g < 2; ++g) {
        float x[16];
        #pragma unroll
        for (int r = 0; r < 16; ++r) x[r] = (g == 0) ? part0[r] : part1[r];

        float q0[8];
        #pragma unroll
        for (int i = 0; i < 8; ++i) {
            const bool b = lane & 1;
            float keep = b ? x[i + 8] : x[i];
            float send = b ? x[i] : x[i + 8];
            q0[i] = keep + __shfl_xor(send, 1);
        }
        float q1[4];
        #pragma unroll
        for (int i = 0; i < 4; ++i) {
            const bool b = lane & 2;
            float keep = b ? q0[i + 4] : q0[i];
            float send = b ? q0[i] : q0[i + 4];
            q1[i] = keep + __shfl_xor(send, 2);
        }
        float q2[2];
        #pragma unroll
        for (int i = 0; i < 2; ++i) {
            const bool b = lane & 4;
            float keep = b ? q1[i + 2] : q1[i];
            float send = b ? q1[i] : q1[i + 2];
            q2[i] = keep + __shfl_xor(send, 4);
        }
        float q3;
        {
            const bool b = lane & 8;
            float keep = b ? q2[1] : q2[0];
            float send = b ? q2[0] : q2[1];
            q3 = keep + __shfl_xor(send, 8);
        }
        float s = q3 + __shfl_xor(q3, 16);
        if (l31 < 16) {
            const int rr  = ((l31 & 1) << 3) | ((l31 & 2) << 1) | ((l31 & 4) >> 1) | ((l31 & 8) >> 3);
            const int row = (rr & 3) + 8 * (rr >> 2) + 4 * lhi;
            logits[rowbase + wave * 64 + g * 32 + row] = s;
        }
    }
}

// ---------------- K3: per-block exp-sum over logits ----------------
__global__ void expsum_kernel(const float* __restrict__ logits, float* __restrict__ blocksum) {
    __shared__ float red[256];
    const int t = threadIdx.x;
    red[t] = expf(logits[blockIdx.x * 256 + t]);
    __syncthreads();
    for (int s = 128; s > 0; s >>= 1) {
        if (t < s) red[t] += red[t + s];
        __syncthreads();
    }
    if (t == 0) blocksum[blockIdx.x] = red[0];
}

// ---------------- K4: normalize ----------------
__global__ void norm_kernel(const float* __restrict__ logits, const float* __restrict__ blocksum,
                            float* __restrict__ out) {
    __shared__ float red[256];
    const int t = threadIdx.x;
    red[t] = blocksum[t];
    __syncthreads();
    for (int s = 128; s > 0; s >>= 1) {
        if (t < s) red[t] += red[t + s];
        __syncthreads();
    }
    const float zinv = 1.0f / red[0];
    const int i = blockIdx.x * 256 + t;
    out[i] = expf(logits[i]) * zinv;
}

extern "C" void kernel_launch(void* const* d_in, const int* in_sizes, int n_in,
                              void* d_out, int out_size, void* d_ws, size_t ws_size,
                              hipStream_t stream) {
    const float* Q    = (const float*)d_in[0];
    const float* Kmat = (const float*)d_in[1];
    const float* Wq   = (const float*)d_in[2];
    const float* bq   = (const float*)d_in[3];
    const float* Wk   = (const float*)d_in[4];
    const float* bk   = (const float*)d_in[5];
    const float* Wout = (const float*)d_in[6];
    float* out = (float*)d_out;

    char* ws = (char*)d_ws;
    _Float16* Wkf   = (_Float16*)(ws);                // 524288 B
    float* v        = (float*)(ws + 524288);          //   2048 B
    float* logits   = (float*)(ws + 526336);          // 262144 B
    float* blocksum = (float*)(ws + 788480);          //   1024 B

    hipLaunchKernelGGL(prep_kernel,   dim3(160),  dim3(256), 0, stream, Q, Wq, bq, Wout, Wk, v, Wkf);
    hipLaunchKernelGGL(score_kernel,  dim3(256),  dim3(256), 0, stream, Kmat, Wkf, bk, v, logits);
    hipLaunchKernelGGL(expsum_kernel, dim3(256),  dim3(256), 0, stream, logits, blocksum);
    hipLaunchKernelGGL(norm_kernel,   dim3(256),  dim3(256), 0, stream, logits, blocksum, out);
}

// Round 15
// 64.574 us; speedup vs baseline: 1.0562x; 1.0562x over previous
//
#include <hip/hip_runtime.h>
#include <hip/hip_fp16.h>

#define CDIM 512
#define ROWS 65536
#define NSTEPS 16     // K-steps of 32

typedef _Float16 half8  __attribute__((ext_vector_type(8)));
typedef __fp16   fp16x2 __attribute__((ext_vector_type(2)));
typedef float    f32x16 __attribute__((ext_vector_type(16)));

// async global->LDS, 16B per lane; LDS dest = wave-uniform base + lane*16
#define GLD_LDS16(gp, lp) __builtin_amdgcn_global_load_lds( \
    (const __attribute__((address_space(1))) unsigned int*)(gp), \
    (__attribute__((address_space(3))) unsigned int*)(lp), 16, 0, 0)

__device__ __forceinline__ half8 cvt8(float4 f0, float4 f1) {
    union { fp16x2 h2[4]; half8 h8; } u;
    u.h2[0] = __builtin_amdgcn_cvt_pkrtz(f0.x, f0.y);
    u.h2[1] = __builtin_amdgcn_cvt_pkrtz(f0.z, f0.w);
    u.h2[2] = __builtin_amdgcn_cvt_pkrtz(f1.x, f1.y);
    u.h2[3] = __builtin_amdgcn_cvt_pkrtz(f1.z, f1.w);
    return u.h8;
}

// ---------------- K1 (fused): blocks 0..31 qproj, blocks 32..159 wkfrag ----------------
__global__ void prep_kernel(const float* __restrict__ Q, const float* __restrict__ Wq,
                            const float* __restrict__ bq, const float* __restrict__ Wout,
                            const float* __restrict__ Wk,
                            float* __restrict__ v, _Float16* __restrict__ Wkf) {
    __shared__ float qs[CDIM];
    const int t = threadIdx.x;
    if (blockIdx.x < 32) {
        // v[j] = relu(Q.Wq[j,:]+bq[j]) * Wout[j/64] / 8 ; bout dropped (softmax shift-invariant)
        qs[t] = Q[t]; qs[t + 256] = Q[t + 256];
        __syncthreads();
        const int jj  = t >> 4;
        const int sub = t & 15;
        const int j   = blockIdx.x * 16 + jj;
        const float4* w4 = (const float4*)(Wq + (size_t)j * CDIM + sub * 32);
        const float4* q4 = (const float4*)(qs + sub * 32);
        float s = 0.f;
        #pragma unroll
        for (int i = 0; i < 8; ++i) {
            float4 w = w4[i]; float4 q = q4[i];
            s = fmaf(w.x, q.x, s); s = fmaf(w.y, q.y, s);
            s = fmaf(w.z, q.z, s); s = fmaf(w.w, q.w, s);
        }
        s += __shfl_xor(s, 1); s += __shfl_xor(s, 2);
        s += __shfl_xor(s, 4); s += __shfl_xor(s, 8);
        if (sub == 0) {
            s += bq[j];
            s = fmaxf(s, 0.f);
            v[j] = s * Wout[j >> 6] * 0.125f;
        }
    } else {
        // Wk -> fp16 B-fragments [jb 0..15][kc 0..31][lane 0..63][8 halfs]
        // frag(jb,kc) lane l: B[k=kc*16+(l>>5)*8+e][j=jb*32+(l&31)]
        const int gid = (blockIdx.x - 32) * 256 + t;
        const int jb  = gid >> 11;
        const int kc  = (gid >> 6) & 31;
        const int l   = gid & 63;
        const int j   = jb * 32 + (l & 31);
        const int k   = kc * 16 + (l >> 5) * 8;
        const float* src = Wk + (size_t)j * CDIM + k;
        float4 f0 = *(const float4*)(src);
        float4 f1 = *(const float4*)(src + 4);
        *(half8*)(Wkf + (size_t)gid * 8) = cvt8(f0, f1);
    }
}

// ---------------- K2: canonical tiled GEMM 128x256(class) x K-step 32 -------------------
// grid (512, 2); 256 thr = 4 waves (wm=w>>1 x wn=w&1): per wave 64 rows x 128 j,
// acc[2][4] = 128 VGPRs. Register-blocked: per kcl, 2 A-frags + 4 B-frags -> 8 MFMAs
// (0.75KB LDS per MFMA). LDS 49KB -> 2-3 WGs/CU: independent barrier domains overlap
// A-stream / LDS / MFMA phases across WGs. A reg-staged (issue-early/write-late),
// B via global_load_lds. Partner classes (bx, bx+512) share XCD -> A rows L2-hot.
__global__ __launch_bounds__(256, 2) void score_kernel(
    const float* __restrict__ Kmat, const _Float16* __restrict__ Wkf,
    const float* __restrict__ bk, const float* __restrict__ v,
    float* __restrict__ partial2)
{
    __shared__ alignas(16) char Ab[2][8192];    // frags (MB*2+kcl)*1024, MB 0..3
    __shared__ alignas(16) char Bb[2][16384];   // frags (nb*2+kcl)*1024,  nb 0..7
    __shared__ float scr[4][2][32];

    const int tid  = threadIdx.x;
    const int lane = tid & 63;
    const int wave = tid >> 6;          // 0..3
    const int l31  = lane & 31;
    const int lhi  = lane >> 5;
    const int wm   = wave >> 1;
    const int wn   = wave & 1;
    const int cls  = blockIdx.y;
    const int rowbase = blockIdx.x * 128;

    // A staging geometry: thread stages frag(MB=wave, kcl 0..1), slot=lane
    //   row = rowbase + wave*32 + (lane&31), k = ks*32 + kcl*16 + (lane>>5)*8
    const float* gA = Kmat + (size_t)(rowbase + wave * 32 + l31) * CDIM + lhi * 8;
    // B staging: wave w DMAs frags (nb = w*2+nbl, kcl), jb = cls*8 + nb
    const char* gB = (const char*)Wkf + (size_t)(cls * 8) * 32768;

    f32x16 acc[2][4];
    #pragma unroll
    for (int mb = 0; mb < 2; ++mb)
        #pragma unroll
        for (int nb = 0; nb < 4; ++nb)
            #pragma unroll
            for (int r = 0; r < 16; ++r) acc[mb][nb][r] = 0.f;

    // ---- prologue: stage A(0) directly, DMA B(0) ----
    #pragma unroll
    for (int kcl = 0; kcl < 2; ++kcl) {
        float4 f0 = *(const float4*)(gA + kcl * 16);
        float4 f1 = *(const float4*)(gA + kcl * 16 + 4);
        *(half8*)(Ab[0] + (wave * 2 + kcl) * 1024 + lane * 16) = cvt8(f0, f1);
        #pragma unroll
        for (int nbl = 0; nbl < 2; ++nbl) {
            const int nb = wave * 2 + nbl;
            GLD_LDS16(gB + ((size_t)nb * 32 + kcl) * 1024 + lane * 16,
                      Bb[0] + (nb * 2 + kcl) * 1024 + lane * 16);
        }
    }
    __syncthreads();

    float4 R[2][2];   // A(ks+1) in flight: [kcl][half]

    for (int ks = 0; ks < NSTEPS; ++ks) {
        const int cur = ks & 1;
        const bool pf = (ks + 1 < NSTEPS);

        // ---- issue-early: R <- A(ks+1); B-DMA(ks+1) -> other buffers ----
        if (pf) {
            const float* ga = gA + (ks + 1) * 32;
            #pragma unroll
            for (int kcl = 0; kcl < 2; ++kcl) {
                R[kcl][0] = *(const float4*)(ga + kcl * 16);
                R[kcl][1] = *(const float4*)(ga + kcl * 16 + 4);
                #pragma unroll
                for (int nbl = 0; nbl < 2; ++nbl) {
                    const int nb = wave * 2 + nbl;
                    GLD_LDS16(gB + ((size_t)nb * 32 + (ks + 1) * 2 + kcl) * 1024 + lane * 16,
                              Bb[cur ^ 1] + (nb * 2 + kcl) * 1024 + lane * 16);
                }
            }
        }
        __builtin_amdgcn_sched_barrier(0);

        // ---- compute: 2 kcl x (2 A-frags + 4 B-frags -> 8 MFMAs) ----
        #pragma unroll
        for (int kcl = 0; kcl < 2; ++kcl) {
            half8 a0 = *(const half8*)(Ab[cur] + ((wm * 2 + 0) * 2 + kcl) * 1024 + lane * 16);
            half8 a1 = *(const half8*)(Ab[cur] + ((wm * 2 + 1) * 2 + kcl) * 1024 + lane * 16);
            half8 b0 = *(const half8*)(Bb[cur] + ((wn * 4 + 0) * 2 + kcl) * 1024 + lane * 16);
            half8 b1 = *(const half8*)(Bb[cur] + ((wn * 4 + 1) * 2 + kcl) * 1024 + lane * 16);
            half8 b2 = *(const half8*)(Bb[cur] + ((wn * 4 + 2) * 2 + kcl) * 1024 + lane * 16);
            half8 b3 = *(const half8*)(Bb[cur] + ((wn * 4 + 3) * 2 + kcl) * 1024 + lane * 16);
            acc[0][0] = __builtin_amdgcn_mfma_f32_32x32x16_f16(a0, b0, acc[0][0], 0, 0, 0);
            acc[0][1] = __builtin_amdgcn_mfma_f32_32x32x16_f16(a0, b1, acc[0][1], 0, 0, 0);
            acc[0][2] = __builtin_amdgcn_mfma_f32_32x32x16_f16(a0, b2, acc[0][2], 0, 0, 0);
            acc[0][3] = __builtin_amdgcn_mfma_f32_32x32x16_f16(a0, b3, acc[0][3], 0, 0, 0);
            acc[1][0] = __builtin_amdgcn_mfma_f32_32x32x16_f16(a1, b0, acc[1][0], 0, 0, 0);
            acc[1][1] = __builtin_amdgcn_mfma_f32_32x32x16_f16(a1, b1, acc[1][1], 0, 0, 0);
            acc[1][2] = __builtin_amdgcn_mfma_f32_32x32x16_f16(a1, b2, acc[1][2], 0, 0, 0);
            acc[1][3] = __builtin_amdgcn_mfma_f32_32x32x16_f16(a1, b3, acc[1][3], 0, 0, 0);
        }
        __builtin_amdgcn_sched_barrier(0);

        // ---- write-late: R -> Ab[other] ----
        if (pf) {
            #pragma unroll
            for (int kcl = 0; kcl < 2; ++kcl)
                *(half8*)(Ab[cur ^ 1] + (wave * 2 + kcl) * 1024 + lane * 16)
                    = cvt8(R[kcl][0], R[kcl][1]);
        }
        __syncthreads();
    }

    // ---- epilogue: relu + v-weight over 4 nb, fold-tree per mb ----
    float bj[4], vj[4];
    #pragma unroll
    for (int nb = 0; nb < 4; ++nb) {
        const int j = cls * 256 + (wn * 4 + nb) * 32 + l31;
        bj[nb] = bk[j];
        vj[nb] = v[j];
    }

    #pragma unroll
    for (int mb = 0; mb < 2; ++mb) {
        float part[16];
        #pragma unroll
        for (int r = 0; r < 16; ++r) {
            float s = 0.f;
            #pragma unroll
            for (int nb = 0; nb < 4; ++nb)
                s += fmaxf(acc[mb][nb][r] + bj[nb], 0.f) * vj[nb];
            part[r] = s;
        }

        float q0[8];
        #pragma unroll
        for (int i = 0; i < 8; ++i) {
            const bool b = lane & 1;
            float keep = b ? part[i + 8] : part[i];
            float send = b ? part[i] : part[i + 8];
            q0[i] = keep + __shfl_xor(send, 1);
        }
        float q1[4];
        #pragma unroll
        for (int i = 0; i < 4; ++i) {
            const bool b = lane & 2;
            float keep = b ? q0[i + 4] : q0[i];
            float send = b ? q0[i] : q0[i + 4];
            q1[i] = keep + __shfl_xor(send, 2);
        }
        float q2[2];
        #pragma unroll
        for (int i = 0; i < 2; ++i) {
            const bool b = lane & 4;
            float keep = b ? q1[i + 2] : q1[i];
            float send = b ? q1[i] : q1[i + 2];
            q2[i] = keep + __shfl_xor(send, 4);
        }
        float q3;
        {
            const bool b = lane & 8;
            float keep = b ? q2[1] : q2[0];
            float send = b ? q2[0] : q2[1];
            q3 = keep + __shfl_xor(send, 8);
        }
        float s = q3 + __shfl_xor(q3, 16);
        if (l31 < 16) {
            const int rr  = ((l31 & 1) << 3) | ((l31 & 2) << 1) | ((l31 & 4) >> 1) | ((l31 & 8) >> 3);
            const int row = (rr & 3) + 8 * (rr >> 2) + 4 * lhi;
            scr[wm * 2 + mb][wn][row] = s;
        }
    }
    __syncthreads();

    if (tid < 128) {
        const int rb = tid >> 5;
        const int r  = tid & 31;
        partial2[(size_t)cls * ROWS + rowbase + rb * 32 + r] = scr[rb][0][r] + scr[rb][1][r];
    }
}

// ---------------- K3: merge 2 classes, store logits, per-block exp-sum ----------------
__global__ void expsum_kernel(const float* __restrict__ partial2, float* __restrict__ logits,
                              float* __restrict__ blocksum) {
    __shared__ float red[256];
    const int t = threadIdx.x;
    const int row = blockIdx.x * 256 + t;
    const float lg = partial2[row] + partial2[ROWS + row];
    logits[row] = lg;
    red[t] = expf(lg);
    __syncthreads();
    for (int s = 128; s > 0; s >>= 1) {
        if (t < s) red[t] += red[t + s];
        __syncthreads();
    }
    if (t == 0) blocksum[blockIdx.x] = red[0];
}

// ---------------- K4: normalize ----------------
__global__ void norm_kernel(const float* __restrict__ logits, const float* __restrict__ blocksum,
                            float* __restrict__ out) {
    __shared__ float red[256];
    const int t = threadIdx.x;
    red[t] = blocksum[t];
    __syncthreads();
    for (int s = 128; s > 0; s >>= 1) {
        if (t < s) red[t] += red[t + s];
        __syncthreads();
    }
    const float zinv = 1.0f / red[0];
    const int i = blockIdx.x * 256 + t;
    out[i] = expf(logits[i]) * zinv;
}

extern "C" void kernel_launch(void* const* d_in, const int* in_sizes, int n_in,
                              void* d_out, int out_size, void* d_ws, size_t ws_size,
                              hipStream_t stream) {
    const float* Q    = (const float*)d_in[0];
    const float* Kmat = (const float*)d_in[1];
    const float* Wq   = (const float*)d_in[2];
    const float* bq   = (const float*)d_in[3];
    const float* Wk   = (const float*)d_in[4];
    const float* bk   = (const float*)d_in[5];
    const float* Wout = (const float*)d_in[6];
    float* out = (float*)d_out;

    char* ws = (char*)d_ws;
    _Float16* Wkf   = (_Float16*)(ws);                // 524288 B
    float* v        = (float*)(ws + 524288);          //   2048 B
    float* partial2 = (float*)(ws + 526336);          // 524288 B (2 classes x 65536)
    float* logits   = (float*)(ws + 1050624);         // 262144 B
    float* blocksum = (float*)(ws + 1312768);         //   1024 B

    hipLaunchKernelGGL(prep_kernel,   dim3(160),     dim3(256), 0, stream, Q, Wq, bq, Wout, Wk, v, Wkf);
    hipLaunchKernelGGL(score_kernel,  dim3(512, 2),  dim3(256), 0, stream, Kmat, Wkf, bk, v, partial2);
    hipLaunchKernelGGL(expsum_kernel, dim3(256),     dim3(256), 0, stream, partial2, logits, blocksum);
    hipLaunchKernelGGL(norm_kernel,   dim3(256),     dim3(256), 0, stream, logits, blocksum, out);
}

// Round 17
// 63.155 us; speedup vs baseline: 1.0799x; 1.0225x over previous
//
#include <hip/hip_runtime.h>
#include <hip/hip_fp16.h>

#define CDIM 512
#define ROWS 65536
#define NSTEPS 16     // K-steps of 32

typedef _Float16 half8  __attribute__((ext_vector_type(8)));
typedef __fp16   fp16x2 __attribute__((ext_vector_type(2)));
typedef float    f32x16 __attribute__((ext_vector_type(16)));

// async global->LDS, 16B per lane; LDS dest = wave-uniform base + lane*16
#define GLD_LDS16(gp, lp) __builtin_amdgcn_global_load_lds( \
    (const __attribute__((address_space(1))) unsigned int*)(gp), \
    (__attribute__((address_space(3))) unsigned int*)(lp), 16, 0, 0)

__device__ __forceinline__ half8 cvt8(float4 f0, float4 f1) {
    union { fp16x2 h2[4]; half8 h8; } u;
    u.h2[0] = __builtin_amdgcn_cvt_pkrtz(f0.x, f0.y);
    u.h2[1] = __builtin_amdgcn_cvt_pkrtz(f0.z, f0.w);
    u.h2[2] = __builtin_amdgcn_cvt_pkrtz(f1.x, f1.y);
    u.h2[3] = __builtin_amdgcn_cvt_pkrtz(f1.z, f1.w);
    return u.h8;
}

// ---------------- K1 (fused): blocks 0..31 qproj, blocks 32..159 wkfrag ----------------
__global__ void prep_kernel(const float* __restrict__ Q, const float* __restrict__ Wq,
                            const float* __restrict__ bq, const float* __restrict__ Wout,
                            const float* __restrict__ Wk,
                            float* __restrict__ v, _Float16* __restrict__ Wkf) {
    __shared__ float qs[CDIM];
    const int t = threadIdx.x;
    if (blockIdx.x < 32) {
        // v[j] = relu(Q.Wq[j,:]+bq[j]) * Wout[j/64] / 8 ; bout dropped (softmax shift-invariant)
        qs[t] = Q[t]; qs[t + 256] = Q[t + 256];
        __syncthreads();
        const int jj  = t >> 4;
        const int sub = t & 15;
        const int j   = blockIdx.x * 16 + jj;
        const float4* w4 = (const float4*)(Wq + (size_t)j * CDIM + sub * 32);
        const float4* q4 = (const float4*)(qs + sub * 32);
        float s = 0.f;
        #pragma unroll
        for (int i = 0; i < 8; ++i) {
            float4 w = w4[i]; float4 q = q4[i];
            s = fmaf(w.x, q.x, s); s = fmaf(w.y, q.y, s);
            s = fmaf(w.z, q.z, s); s = fmaf(w.w, q.w, s);
        }
        s += __shfl_xor(s, 1); s += __shfl_xor(s, 2);
        s += __shfl_xor(s, 4); s += __shfl_xor(s, 8);
        if (sub == 0) {
            s += bq[j];
            s = fmaxf(s, 0.f);
            v[j] = s * Wout[j >> 6] * 0.125f;
        }
    } else {
        // Wk -> fp16 B-fragments [jb 0..15][kc 0..31][lane 0..63][8 halfs]
        // frag(jb,kc) lane l: B[k=kc*16+(l>>5)*8+e][j=jb*32+(l&31)]
        const int gid = (blockIdx.x - 32) * 256 + t;
        const int jb  = gid >> 11;
        const int kc  = (gid >> 6) & 31;
        const int l   = gid & 63;
        const int j   = jb * 32 + (l & 31);
        const int k   = kc * 16 + (l >> 5) * 8;
        const float* src = Wk + (size_t)j * CDIM + k;
        float4 f0 = *(const float4*)(src);
        float4 f1 = *(const float4*)(src + 4);
        *(half8*)(Wkf + (size_t)gid * 8) = cvt8(f0, f1);
    }
}

// ---------------- K2: tiled GEMM 128x256(class) x K-step 32, coalesced A-staging --------
// grid (1024): cls = bid&1, rowblock = bid>>1 -> class partners dispatch-adjacent
// (twin K rows L2/L3-hot). A-staging: thread (sr=tid>>2 in 0..63, sc=tid&3) reads 32B
// contiguous of rows sr AND sr+64 (wave instr = 16 full 128B lines each), two
// ds_write_b128 into frag-major LDS. B via global_load_lds. 4 waves; acc[2][4]; 2 WGs/CU.
__global__ __launch_bounds__(256, 2) void score_kernel(
    const float* __restrict__ Kmat, const _Float16* __restrict__ Wkf,
    const float* __restrict__ bk, const float* __restrict__ v,
    float* __restrict__ partial2)
{
    __shared__ alignas(16) char Ab[2][8192];    // frags (MB*2+kcl)*1024, MB 0..3
    __shared__ alignas(16) char Bb[2][16384];   // frags (nb*2+kcl)*1024,  nb 0..7
    __shared__ float scr[4][2][32];

    const int tid  = threadIdx.x;
    const int lane = tid & 63;
    const int wave = tid >> 6;          // 0..3
    const int l31  = lane & 31;
    const int lhi  = lane >> 5;
    const int wm   = wave >> 1;
    const int wn   = wave & 1;
    const int cls  = blockIdx.x & 1;
    const int rowbase = (blockIdx.x >> 1) * 128;

    // A staging (coalesced): thread covers rows sr and sr+64, 8-float chunk sc
    const int sr = tid >> 2;            // 0..63
    const int sc = tid & 3;             // 0..3
    const float* gA0 = Kmat + (size_t)(rowbase + sr) * CDIM + sc * 8;
    const float* gA1 = gA0 + (size_t)64 * CDIM;
    // LDS dests: frag = (row>>5)*2 + (sc>>1); slot = (row&31) + ((sc&1)<<5)
    const int adst0 = (((sr >> 5) * 2 + (sc >> 1)) << 10) + (((sr & 31) + ((sc & 1) << 5)) << 4);
    const int adst1 = adst0 + 4096;     // rows sr+64: frag index +2 -> +4KB
    // B staging: wave w DMAs frags (nb = w*2+nbl, kcl), jb = cls*8 + nb
    const char* gB = (const char*)Wkf + (size_t)(cls * 8) * 32768;

    f32x16 acc[2][4];
    #pragma unroll
    for (int mb = 0; mb < 2; ++mb)
        #pragma unroll
        for (int nb = 0; nb < 4; ++nb)
            #pragma unroll
            for (int r = 0; r < 16; ++r) acc[mb][nb][r] = 0.f;

    // ---- prologue: stage A(0) directly, DMA B(0) ----
    {
        float4 f0 = *(const float4*)(gA0);
        float4 f1 = *(const float4*)(gA0 + 4);
        float4 f2 = *(const float4*)(gA1);
        float4 f3 = *(const float4*)(gA1 + 4);
        *(half8*)(Ab[0] + adst0) = cvt8(f0, f1);
        *(half8*)(Ab[0] + adst1) = cvt8(f2, f3);
        #pragma unroll
        for (int kcl = 0; kcl < 2; ++kcl)
            #pragma unroll
            for (int nbl = 0; nbl < 2; ++nbl) {
                const int nb = wave * 2 + nbl;
                GLD_LDS16(gB + ((size_t)nb * 32 + kcl) * 1024 + lane * 16,
                          Bb[0] + (nb * 2 + kcl) * 1024 + lane * 16);
            }
    }
    __syncthreads();

    float4 R0, R1, R2, R3;   // A(ks+1) in flight (rows sr, sr+64)

    for (int ks = 0; ks < NSTEPS; ++ks) {
        const int cur = ks & 1;
        const bool pf = (ks + 1 < NSTEPS);

        // ---- issue-early: R <- A(ks+1); B-DMA(ks+1) -> other buffers ----
        if (pf) {
            const float* ga0 = gA0 + (ks + 1) * 32;
            const float* ga1 = gA1 + (ks + 1) * 32;
            R0 = *(const float4*)(ga0);
            R1 = *(const float4*)(ga0 + 4);
            R2 = *(const float4*)(ga1);
            R3 = *(const float4*)(ga1 + 4);
            #pragma unroll
            for (int kcl = 0; kcl < 2; ++kcl)
                #pragma unroll
                for (int nbl = 0; nbl < 2; ++nbl) {
                    const int nb = wave * 2 + nbl;
                    GLD_LDS16(gB + ((size_t)nb * 32 + (ks + 1) * 2 + kcl) * 1024 + lane * 16,
                              Bb[cur ^ 1] + (nb * 2 + kcl) * 1024 + lane * 16);
                }
        }
        __builtin_amdgcn_sched_barrier(0);

        // ---- compute: 2 kcl x (2 A-frags + 4 B-frags -> 8 MFMAs) ----
        #pragma unroll
        for (int kcl = 0; kcl < 2; ++kcl) {
            half8 a0 = *(const half8*)(Ab[cur] + ((wm * 2 + 0) * 2 + kcl) * 1024 + lane * 16);
            half8 a1 = *(const half8*)(Ab[cur] + ((wm * 2 + 1) * 2 + kcl) * 1024 + lane * 16);
            half8 b0 = *(const half8*)(Bb[cur] + ((wn * 4 + 0) * 2 + kcl) * 1024 + lane * 16);
            half8 b1 = *(const half8*)(Bb[cur] + ((wn * 4 + 1) * 2 + kcl) * 1024 + lane * 16);
            half8 b2 = *(const half8*)(Bb[cur] + ((wn * 4 + 2) * 2 + kcl) * 1024 + lane * 16);
            half8 b3 = *(const half8*)(Bb[cur] + ((wn * 4 + 3) * 2 + kcl) * 1024 + lane * 16);
            acc[0][0] = __builtin_amdgcn_mfma_f32_32x32x16_f16(a0, b0, acc[0][0], 0, 0, 0);
            acc[0][1] = __builtin_amdgcn_mfma_f32_32x32x16_f16(a0, b1, acc[0][1], 0, 0, 0);
            acc[0][2] = __builtin_amdgcn_mfma_f32_32x32x16_f16(a0, b2, acc[0][2], 0, 0, 0);
            acc[0][3] = __builtin_amdgcn_mfma_f32_32x32x16_f16(a0, b3, acc[0][3], 0, 0, 0);
            acc[1][0] = __builtin_amdgcn_mfma_f32_32x32x16_f16(a1, b0, acc[1][0], 0, 0, 0);
            acc[1][1] = __builtin_amdgcn_mfma_f32_32x32x16_f16(a1, b1, acc[1][1], 0, 0, 0);
            acc[1][2] = __builtin_amdgcn_mfma_f32_32x32x16_f16(a1, b2, acc[1][2], 0, 0, 0);
            acc[1][3] = __builtin_amdgcn_mfma_f32_32x32x16_f16(a1, b3, acc[1][3], 0, 0, 0);
        }
        __builtin_amdgcn_sched_barrier(0);

        // ---- write-late: R -> Ab[other] (two ds_write_b128) ----
        if (pf) {
            *(half8*)(Ab[cur ^ 1] + adst0) = cvt8(R0, R1);
            *(half8*)(Ab[cur ^ 1] + adst1) = cvt8(R2, R3);
        }
        __syncthreads();
    }

    // ---- epilogue: relu + v-weight over 4 nb, fold-tree per mb ----
    float bj[4], vj[4];
    #pragma unroll
    for (int nb = 0; nb < 4; ++nb) {
        const int j = cls * 256 + (wn * 4 + nb) * 32 + l31;
        bj[nb] = bk[j];
        vj[nb] = v[j];
    }

    #pragma unroll
    for (int mb = 0; mb < 2; ++mb) {
        float part[16];
        #pragma unroll
        for (int r = 0; r < 16; ++r) {
            float s = 0.f;
            #pragma unroll
            for (int nb = 0; nb < 4; ++nb)
                s += fmaxf(acc[mb][nb][r] + bj[nb], 0.f) * vj[nb];
            part[r] = s;
        }

        float q0[8];
        #pragma unroll
        for (int i = 0; i < 8; ++i) {
            const bool b = lane & 1;
            float keep = b ? part[i + 8] : part[i];
            float send = b ? part[i] : part[i + 8];
            q0[i] = keep + __shfl_xor(send, 1);
        }
        float q1[4];
        #pragma unroll
        for (int i = 0; i < 4; ++i) {
            const bool b = lane & 2;
            float keep = b ? q0[i + 4] : q0[i];
            float send = b ? q0[i] : q0[i + 4];
            q1[i] = keep + __shfl_xor(send, 2);
        }
        float q2[2];
        #pragma unroll
        for (int i = 0; i < 2; ++i) {
            const bool b = lane & 4;
            float keep = b ? q1[i + 2] : q1[i];
            float send = b ? q1[i] : q1[i + 2];
            q2[i] = keep + __shfl_xor(send, 4);
        }
        float q3;
        {
            const bool b = lane & 8;
            float keep = b ? q2[1] : q2[0];
            float send = b ? q2[0] : q2[1];
            q3 = keep + __shfl_xor(send, 8);
        }
        float s = q3 + __shfl_xor(q3, 16);
        if (l31 < 16) {
            const int rr  = ((l31 & 1) << 3) | ((l31 & 2) << 1) | ((l31 & 4) >> 1) | ((l31 & 8) >> 3);
            const int row = (rr & 3) + 8 * (rr >> 2) + 4 * lhi;
            scr[wm * 2 + mb][wn][row] = s;
        }
    }
    __syncthreads();

    if (tid < 128) {
        const int rb = tid >> 5;
        const int r  = tid & 31;
        partial2[(size_t)cls * ROWS + rowbase + rb * 32 + r] = scr[rb][0][r] + scr[rb][1][r];
    }
}

// ---------------- K3: merge 2 classes, store logits, per-block exp-sum ----------------
__global__ void expsum_kernel(const float* __restrict__ partial2, float* __restrict__ logits,
                              float* __restrict__ blocksum) {
    __shared__ float red[256];
    const int t = threadIdx.x;
    const int row = blockIdx.x * 256 + t;
    const float lg = partial2[row] + partial2[ROWS + row];
    logits[row] = lg;
    red[t] = expf(lg);
    __syncthreads();
    for (int s = 128; s > 0; s >>= 1) {
        if (t < s) red[t] += red[t + s];
        __syncthreads();
    }
    if (t == 0) blocksum[blockIdx.x] = red[0];
}

// ---------------- K4: normalize ----------------
__global__ void norm_kernel(const float* __restrict__ logits, const float* __restrict__ blocksum,
                            float* __restrict__ out) {
    __shared__ float red[256];
    const int t = threadIdx.x;
    red[t] = blocksum[t];
    __syncthreads();
    for (int s = 128; s > 0; s >>= 1) {
        if (t < s) red[t] += red[t + s];
        __syncthreads();
    }
    const float zinv = 1.0f / red[0];
    const int i = blockIdx.x * 256 + t;
    out[i] = expf(logits[i]) * zinv;
}

extern "C" void kernel_launch(void* const* d_in, const int* in_sizes, int n_in,
                              void* d_out, int out_size, void* d_ws, size_t ws_size,
                              hipStream_t stream) {
    const float* Q    = (const float*)d_in[0];
    const float* Kmat = (const float*)d_in[1];
    const float* Wq   = (const float*)d_in[2];
    const float* bq   = (const float*)d_in[3];
    const float* Wk   = (const float*)d_in[4];
    const float* bk   = (const float*)d_in[5];
    const float* Wout = (const float*)d_in[6];
    float* out = (float*)d_out;

    char* ws = (char*)d_ws;
    _Float16* Wkf   = (_Float16*)(ws);                // 524288 B
    float* v        = (float*)(ws + 524288);          //   2048 B
    float* partial2 = (float*)(ws + 526336);          // 524288 B (2 classes x 65536)
    float* logits   = (float*)(ws + 1050624);         // 262144 B
    float* blocksum = (float*)(ws + 1312768);         //   1024 B

    hipLaunchKernelGGL(prep_kernel,   dim3(160),   dim3(256), 0, stream, Q, Wq, bq, Wout, Wk, v, Wkf);
    hipLaunchKernelGGL(score_kernel,  dim3(1024),  dim3(256), 0, stream, Kmat, Wkf, bk, v, partial2);
    hipLaunchKernelGGL(expsum_kernel, dim3(256),   dim3(256), 0, stream, partial2, logits, blocksum);
    hipLaunchKernelGGL(norm_kernel,   dim3(256),   dim3(256), 0, stream, logits, blocksum, out);
}